// Round 9
// baseline (38.111 us; speedup 1.0000x reference)
//
#include <hip/hip_runtime.h>
#include <hip/hip_bf16.h>

#define ALPHA_C 0.3f
#define BETHE_C 1.2f
#define CH 4    // j-tiles per block = 4 waves, one tile per wave

typedef __attribute__((ext_vector_type(8))) short  frag_ab;   // 8 bf16 = 4 VGPR
typedef __attribute__((ext_vector_type(4))) float  frag_cd;   // 4 fp32 acc

// fp32 -> bf16 round-to-nearest-even
static __device__ __forceinline__ unsigned short f2bf(float f) {
    union { float f; unsigned int u; } cv;
    cv.f = f;
    unsigned int x = cv.u;
    unsigned int r = (x + 0x7fffu + ((x >> 16) & 1u)) >> 16;
    return (unsigned short)r;
}

__global__ void zero_kernel(float* out) { out[0] = 0.0f; }

// Pre-pass: X fp32 [N][128] -> Xb bf16 in FRAGMENT-LINEAR layout.
// Tile T = R*4 + ks; lane l's 16 B at byte T*1024 + l*16.
__global__ __launch_bounds__(256) void convert_kernel(
    const float* __restrict__ X, unsigned short* __restrict__ Xb, int nrows)
{
    const int tau = blockIdx.x * 256 + threadIdx.x;
    const int total = nrows * 16;
    if (tau >= total) return;
    const int T = tau >> 6;
    const int l = tau & 63;
    const int R  = T >> 2;
    const int ks = T & 3;
    const int row = R * 16 + (l & 15);
    const int k   = ks * 32 + (l >> 4) * 8;
    const float* src = X + (size_t)row * 128 + k;
    float4 a0 = *(const float4*)(src);
    float4 a1 = *(const float4*)(src + 4);
    frag_ab p;
    p[0] = (short)f2bf(a0.x); p[1] = (short)f2bf(a0.y);
    p[2] = (short)f2bf(a0.z); p[3] = (short)f2bf(a0.w);
    p[4] = (short)f2bf(a1.x); p[5] = (short)f2bf(a1.y);
    p[6] = (short)f2bf(a1.z); p[7] = (short)f2bf(a1.w);
    *(frag_ab*)((char*)Xb + (size_t)T * 1024 + l * 16) = p;
}

static __device__ __forceinline__ void load4(
    const unsigned short* __restrict__ Xb, int p /* panel idx */, int ks,
    int l, frag_ab* dst)
{
    #pragma unroll
    for (int m = 0; m < 4; ++m)
        dst[m] = *(const frag_ab*)(Xb + (size_t)((p * 4 + m) * 4 + ks) * 512 + l * 8);
}

static __device__ __forceinline__ void mfma_step(
    const frag_ab* a, const frag_ab* bv, frag_cd acc[4][4])
{
    #pragma unroll
    for (int m = 0; m < 4; ++m)
        #pragma unroll
        for (int n = 0; n < 4; ++n)
            acc[m][n] = __builtin_amdgcn_mfma_f32_16x16x32_bf16(
                a[m], bv[n], acc[m][n], 0, 0, 0);
}

// Main: 256-thread blocks = 4 INDEPENDENT waves; wave w computes one 64x64
// tile (i, j0+w). No LDS, no barriers, no atomics. Proper workgroup packing
// gives 8-12 resident waves/CU to hide L2 latency (the r7 probe showed
// 64-thread blocks packed at only ~3.5 waves/CU).
__global__ __launch_bounds__(256) void margin_wave(
    const unsigned short* __restrict__ Xb, const int* __restrict__ labels,
    float* __restrict__ partials, int NP)
{
    // triangular chunk decode (<= NP scalar iterations, SALU only)
    int b = blockIdx.x;
    int i = 0;
    while (true) {
        const int cnt = (NP - i + CH - 1) / CH;
        if (b < cnt) break;
        b -= cnt; ++i;
    }
    const int w    = threadIdx.x >> 6;          // wave id 0..3
    const int l    = threadIdx.x & 63;
    const int j    = i + b * CH + w;            // this wave's tile column
    const int slot = blockIdx.x * 4 + w;

    if (j >= NP) { if (l == 0) partials[slot] = 0.f; return; }

    // batch-issue loads with 2-set rotation (independent addresses, the
    // compiler groups them into few vmcnt waits = few latency exposures)
    frag_ab A0[4], B0[4], A1[4], B1[4], A2[4], B2[4], A3[4], B3[4];
    load4(Xb, i, 0, l, A0); load4(Xb, j, 0, l, B0);
    load4(Xb, i, 1, l, A1); load4(Xb, j, 1, l, B1);

    int labi[4][4];
    #pragma unroll
    for (int m = 0; m < 4; ++m)
        #pragma unroll
        for (int r4 = 0; r4 < 4; ++r4)
            labi[m][r4] = labels[i * 64 + m * 16 + ((l >> 4) << 2) + r4];
    int labj[4];
    #pragma unroll
    for (int n = 0; n < 4; ++n)
        labj[n] = labels[j * 64 + n * 16 + (l & 15)];

    frag_cd acc[4][4];
    #pragma unroll
    for (int m = 0; m < 4; ++m)
        #pragma unroll
        for (int n = 0; n < 4; ++n)
            acc[m][n] = (frag_cd){0.f, 0.f, 0.f, 0.f};

    mfma_step(A0, B0, acc);
    load4(Xb, i, 2, l, A2); load4(Xb, j, 2, l, B2);
    mfma_step(A1, B1, acc);
    load4(Xb, i, 3, l, A3); load4(Xb, j, 3, l, B3);
    mfma_step(A2, B2, acc);
    mfma_step(A3, B3, acc);

    // hinge epilogue
    float ts = 0.f;
    #pragma unroll
    for (int m = 0; m < 4; ++m) {
        #pragma unroll
        for (int r4 = 0; r4 < 4; ++r4) {
            const int li = labi[m][r4];
            #pragma unroll
            for (int n = 0; n < 4; ++n) {
                const float d = acc[m][n][r4];
                const float v = (li == labj[n])
                    ? (d + (ALPHA_C - BETHE_C))
                    : ((ALPHA_C + BETHE_C) - d);
                ts += fmaxf(v, 0.f);
            }
        }
    }
    ts *= (j == i) ? 1.f : 2.f;

    #pragma unroll
    for (int off = 32; off > 0; off >>= 1)
        ts += __shfl_down(ts, off, 64);
    if (l == 0) partials[slot] = ts;
}

// Final reduce: one block sums partials (fixed order -> deterministic).
__global__ __launch_bounds__(256) void reduce_kernel(
    const float* __restrict__ partials, float* __restrict__ out,
    int n, float inv_n)
{
    __shared__ float wsum[4];
    const int t    = threadIdx.x;
    const int lane = t & 63;
    const int wid  = t >> 6;
    float s = 0.f;
    for (int idx = t; idx < n; idx += 256) s += partials[idx];
    #pragma unroll
    for (int off = 32; off > 0; off >>= 1)
        s += __shfl_down(s, off, 64);
    if (lane == 0) wsum[wid] = s;
    __syncthreads();
    if (t == 0) out[0] = (wsum[0] + wsum[1] + wsum[2] + wsum[3]) * inv_n;
}

// ---------------- fallback (tiny ws / odd N): round-1 fused kernel ----------------
__global__ __launch_bounds__(256) void margin_tile_kernel(
    const float* __restrict__ X, const int* __restrict__ labels,
    float* __restrict__ out, int NT, float inv_n)
{
    __shared__ unsigned short ldsA[128 * 64];
    __shared__ unsigned short ldsB[128 * 64];
    __shared__ int labA[128];
    __shared__ int labB[128];
    __shared__ float wsum[4];

    int b = blockIdx.x;
    int ti = 0;
    while (b >= NT - ti) { b -= NT - ti; ++ti; }
    const int tj = ti + b;

    const int t    = threadIdx.x;
    const int lane = t & 63;
    const int wid  = t >> 6;
    const int wr   = wid >> 1;
    const int wc   = wid & 1;

    const int rowA = ti * 128;
    const int rowB = tj * 128;

    if (t < 128) labA[t] = labels[rowA + t];
    else         labB[t - 128] = labels[rowB + (t - 128)];

    frag_cd acc[4][4];
    #pragma unroll
    for (int m = 0; m < 4; ++m)
        #pragma unroll
        for (int n = 0; n < 4; ++n)
            acc[m][n] = (frag_cd){0.f, 0.f, 0.f, 0.f};

    const int g  = lane >> 4;
    const int rl = lane & 15;

    for (int kh = 0; kh < 2; ++kh) {
        __syncthreads();
        #pragma unroll
        for (int it = 0; it < 4; ++it) {
            const int c  = it * 256 + t;
            const int r  = c >> 3;
            const int c8 = c & 7;
            const float* srcA = X + (size_t)(rowA + r) * 128 + kh * 64 + c8 * 8;
            const float* srcB = X + (size_t)(rowB + r) * 128 + kh * 64 + c8 * 8;
            float4 a0 = *(const float4*)(srcA);
            float4 a1 = *(const float4*)(srcA + 4);
            float4 b0 = *(const float4*)(srcB);
            float4 b1 = *(const float4*)(srcB + 4);
            const int byte = r * 128 + (((c8 << 4)) ^ ((r & 7) << 4));
            frag_ab pa, pb;
            pa[0] = (short)f2bf(a0.x); pa[1] = (short)f2bf(a0.y);
            pa[2] = (short)f2bf(a0.z); pa[3] = (short)f2bf(a0.w);
            pa[4] = (short)f2bf(a1.x); pa[5] = (short)f2bf(a1.y);
            pa[6] = (short)f2bf(a1.z); pa[7] = (short)f2bf(a1.w);
            pb[0] = (short)f2bf(b0.x); pb[1] = (short)f2bf(b0.y);
            pb[2] = (short)f2bf(b0.z); pb[3] = (short)f2bf(b0.w);
            pb[4] = (short)f2bf(b1.x); pb[5] = (short)f2bf(b1.y);
            pb[6] = (short)f2bf(b1.z); pb[7] = (short)f2bf(b1.w);
            *(frag_ab*)((char*)ldsA + byte) = pa;
            *(frag_ab*)((char*)ldsB + byte) = pb;
        }
        __syncthreads();
        #pragma unroll
        for (int ks = 0; ks < 2; ++ks) {
            const int kbyte = ks * 64 + g * 16;
            frag_ab av[4], bv[4];
            #pragma unroll
            for (int m = 0; m < 4; ++m) {
                const int row = wr * 64 + m * 16 + rl;
                av[m] = *(const frag_ab*)((const char*)ldsA +
                            row * 128 + (kbyte ^ ((row & 7) << 4)));
            }
            #pragma unroll
            for (int n = 0; n < 4; ++n) {
                const int row = wc * 64 + n * 16 + rl;
                bv[n] = *(const frag_ab*)((const char*)ldsB +
                            row * 128 + (kbyte ^ ((row & 7) << 4)));
            }
            #pragma unroll
            for (int m = 0; m < 4; ++m)
                #pragma unroll
                for (int n = 0; n < 4; ++n)
                    acc[m][n] = __builtin_amdgcn_mfma_f32_16x16x32_bf16(
                        av[m], bv[n], acc[m][n], 0, 0, 0);
        }
    }

    float lsum = 0.f;
    const int oc  = lane & 15;
    const int orr = (lane >> 4) * 4;

    int lj[4];
    #pragma unroll
    for (int n = 0; n < 4; ++n) lj[n] = labB[wc * 64 + n * 16 + oc];

    #pragma unroll
    for (int m = 0; m < 4; ++m) {
        #pragma unroll
        for (int j = 0; j < 4; ++j) {
            const int li = labA[wr * 64 + m * 16 + orr + j];
            #pragma unroll
            for (int n = 0; n < 4; ++n) {
                const float d = acc[m][n][j];
                const float s = (li == lj[n]) ? 1.f : -1.f;
                lsum += fmaxf(fmaf(s, d - BETHE_C, ALPHA_C), 0.f);
            }
        }
    }

    const float w = (ti == tj) ? 1.f : 2.f;
    lsum *= w * inv_n;

    #pragma unroll
    for (int off = 32; off > 0; off >>= 1)
        lsum += __shfl_down(lsum, off, 64);

    if (lane == 0) wsum[wid] = lsum;
    __syncthreads();
    if (t == 0) atomicAdd(out, wsum[0] + wsum[1] + wsum[2] + wsum[3]);
}

extern "C" void kernel_launch(void* const* d_in, const int* in_sizes, int n_in,
                              void* d_out, int out_size, void* d_ws, size_t ws_size,
                              hipStream_t stream) {
    const float* X      = (const float*)d_in[0];
    const int*   labels = (const int*)d_in[1];
    float*       out    = (float*)d_out;

    const int N = in_sizes[1];               // 8192

    const size_t xb_bytes = (size_t)N * 128 * sizeof(unsigned short);  // 2 MB
    const int NP = N / 64;                   // 128 panels

    // exact triangular chunk count: sum over i of ceil((NP-i)/CH)
    int nblk = 0;
    for (int i = 0; i < NP; ++i) nblk += (NP - i + CH - 1) / CH;   // 2112 @ NP=128
    const int npart = nblk * 4;

    const size_t need = xb_bytes + (size_t)npart * sizeof(float);

    if ((N % 64) == 0 && ws_size >= need) {
        unsigned short* Xb       = (unsigned short*)d_ws;
        float*          partials = (float*)((char*)d_ws + xb_bytes);
        const int cblocks = (N * 16 + 255) / 256;
        convert_kernel<<<cblocks, 256, 0, stream>>>(X, Xb, N);
        margin_wave<<<nblk, 256, 0, stream>>>(Xb, labels, partials, NP);
        reduce_kernel<<<1, 256, 0, stream>>>(partials, out, npart, 1.0f / (float)N);
    } else {
        const int NT = N / 128;
        const int nblocks = NT * (NT + 1) / 2;
        zero_kernel<<<1, 1, 0, stream>>>(out);
        margin_tile_kernel<<<nblocks, 256, 0, stream>>>(X, labels, out, NT, 1.0f / (float)N);
    }
}

// Round 10
// 32.931 us; speedup vs baseline: 1.1573x; 1.1573x over previous
//
#include <hip/hip_runtime.h>
#include <hip/hip_bf16.h>

#define ALPHA_C 0.3f
#define BETHE_C 1.2f

typedef __attribute__((ext_vector_type(8))) short  frag_ab;   // 8 bf16 = 4 VGPR
typedef __attribute__((ext_vector_type(4))) float  frag_cd;   // 4 fp32 acc

// fp32 -> bf16 round-to-nearest-even
static __device__ __forceinline__ unsigned short f2bf(float f) {
    union { float f; unsigned int u; } cv;
    cv.f = f;
    unsigned int x = cv.u;
    unsigned int r = (x + 0x7fffu + ((x >> 16) & 1u)) >> 16;
    return (unsigned short)r;
}

static __device__ __forceinline__ void gl_lds16(const unsigned short* g, unsigned short* l) {
    __builtin_amdgcn_global_load_lds(
        (const __attribute__((address_space(1))) void*)g,
        (__attribute__((address_space(3))) void*)l,
        16, 0, 0);
}

__global__ void zero_kernel(float* out) { out[0] = 0.0f; }

// Pre-pass: fp32 X -> bf16, stored PRE-SWIZZLED (16B k-unit u stored at slot
// u ^ (row&7) within the 256B row).
__global__ __launch_bounds__(256) void convert_kernel(
    const float* __restrict__ X, unsigned short* __restrict__ Xb, int nrows)
{
    const int tau = blockIdx.x * 256 + threadIdx.x;
    const int total = nrows * 16;
    if (tau >= total) return;
    const int row = tau >> 4;
    const int u   = tau & 15;
    const float* src = X + (size_t)row * 128 + u * 8;
    float4 a0 = *(const float4*)(src);
    float4 a1 = *(const float4*)(src + 4);
    frag_ab p;
    p[0] = (short)f2bf(a0.x); p[1] = (short)f2bf(a0.y);
    p[2] = (short)f2bf(a0.z); p[3] = (short)f2bf(a0.w);
    p[4] = (short)f2bf(a1.x); p[5] = (short)f2bf(a1.y);
    p[6] = (short)f2bf(a1.z); p[7] = (short)f2bf(a1.w);
    const int du = u ^ (row & 7);
    *(frag_ab*)((char*)Xb + (size_t)row * 256 + du * 16) = p;
}

// Main: one block = one 128x128 tile of D = X X^T (ti <= tj), bf16 input
// pre-swizzled in global. Staging = pure linear global_load_lds dwordx4.
// Partial per block -> d_ws (no same-address atomics).
__global__ __launch_bounds__(256) void margin_tile_bf16(
    const unsigned short* __restrict__ Xb, const int* __restrict__ labels,
    float* __restrict__ partials, int NT, float inv_n)
{
    __shared__ unsigned short ldsA[128 * 128];   // 32 KB (full K, swizzled)
    __shared__ unsigned short ldsB[128 * 128];   // 32 KB
    __shared__ int labA[128];
    __shared__ int labB[128];
    __shared__ float wsum[4];

    int b = blockIdx.x;
    int ti = 0;
    while (b >= NT - ti) { b -= NT - ti; ++ti; }
    const int tj = ti + b;

    const int t    = threadIdx.x;
    const int lane = t & 63;
    const int wid  = t >> 6;
    const int wr   = wid >> 1;
    const int wc   = wid & 1;

    const int rowA = ti * 128;
    const int rowB = tj * 128;

    if (t < 128) labA[t] = labels[rowA + t];
    else         labB[t - 128] = labels[rowB + (t - 128)];

    // --- stage both panels: each wave linearly copies 8 KB of A and of B ---
    {
        const unsigned short* gA = Xb + (size_t)rowA * 128 + (size_t)wid * 4096 + lane * 8;
        const unsigned short* gB = Xb + (size_t)rowB * 128 + (size_t)wid * 4096 + lane * 8;
        unsigned short* lA = ldsA + wid * 4096;   // wave-uniform LDS base
        unsigned short* lB = ldsB + wid * 4096;
        #pragma unroll
        for (int q = 0; q < 8; ++q) gl_lds16(gA + q * 512, lA + q * 512);
        #pragma unroll
        for (int q = 0; q < 8; ++q) gl_lds16(gB + q * 512, lB + q * 512);
    }

    frag_cd acc[4][4];
    #pragma unroll
    for (int m = 0; m < 4; ++m)
        #pragma unroll
        for (int n = 0; n < 4; ++n)
            acc[m][n] = (frag_cd){0.f, 0.f, 0.f, 0.f};

    __syncthreads();   // drains vmcnt before s_barrier

    const int g  = lane >> 4;
    const int rl = lane & 15;
    const int sw = (rl & 7);

    #pragma unroll
    for (int ks = 0; ks < 4; ++ks) {
        const int U  = ks * 4 + g;
        const int su = (U ^ sw) << 4;
        frag_ab av[4], bv[4];
        #pragma unroll
        for (int m = 0; m < 4; ++m) {
            const int row = wr * 64 + m * 16 + rl;
            av[m] = *(const frag_ab*)((const char*)ldsA + row * 256 + su);
        }
        #pragma unroll
        for (int n = 0; n < 4; ++n) {
            const int row = wc * 64 + n * 16 + rl;
            bv[n] = *(const frag_ab*)((const char*)ldsB + row * 256 + su);
        }
        #pragma unroll
        for (int m = 0; m < 4; ++m)
            #pragma unroll
            for (int n = 0; n < 4; ++n)
                acc[m][n] = __builtin_amdgcn_mfma_f32_16x16x32_bf16(
                    av[m], bv[n], acc[m][n], 0, 0, 0);
    }

    // --- epilogue: hinge + reduce (C/D: col=lane&15, row=(lane>>4)*4+reg) ---
    float lsum = 0.f;
    const int oc  = lane & 15;
    const int orr = (lane >> 4) * 4;

    int lj[4];
    #pragma unroll
    for (int n = 0; n < 4; ++n) lj[n] = labB[wc * 64 + n * 16 + oc];

    #pragma unroll
    for (int m = 0; m < 4; ++m) {
        #pragma unroll
        for (int j = 0; j < 4; ++j) {
            const int li = labA[wr * 64 + m * 16 + orr + j];
            #pragma unroll
            for (int n = 0; n < 4; ++n) {
                const float d = acc[m][n][j];
                const float s = (li == lj[n]) ? 1.f : -1.f;
                lsum += fmaxf(fmaf(s, d - BETHE_C, ALPHA_C), 0.f);
            }
        }
    }

    const float w = (ti == tj) ? 1.f : 2.f;
    lsum *= w * inv_n;

    #pragma unroll
    for (int off = 32; off > 0; off >>= 1)
        lsum += __shfl_down(lsum, off, 64);

    if (lane == 0) wsum[wid] = lsum;
    __syncthreads();
    if (t == 0) partials[blockIdx.x] = wsum[0] + wsum[1] + wsum[2] + wsum[3];
}

// Final reduce: one block sums the per-tile partials into out[0].
__global__ __launch_bounds__(256) void reduce_kernel(
    const float* __restrict__ partials, float* __restrict__ out, int n)
{
    __shared__ float wsum[4];
    const int t    = threadIdx.x;
    const int lane = t & 63;
    const int wid  = t >> 6;
    float s = 0.f;
    for (int i = t; i < n; i += 256) s += partials[i];
    #pragma unroll
    for (int off = 32; off > 0; off >>= 1)
        s += __shfl_down(s, off, 64);
    if (lane == 0) wsum[wid] = s;
    __syncthreads();
    if (t == 0) out[0] = wsum[0] + wsum[1] + wsum[2] + wsum[3];
}

// ---------------- fallback (ws too small): round-1 fused kernel ----------------
__global__ __launch_bounds__(256) void margin_tile_kernel(
    const float* __restrict__ X, const int* __restrict__ labels,
    float* __restrict__ out, int NT, float inv_n)
{
    __shared__ unsigned short ldsA[128 * 64];
    __shared__ unsigned short ldsB[128 * 64];
    __shared__ int labA[128];
    __shared__ int labB[128];
    __shared__ float wsum[4];

    int b = blockIdx.x;
    int ti = 0;
    while (b >= NT - ti) { b -= NT - ti; ++ti; }
    const int tj = ti + b;

    const int t    = threadIdx.x;
    const int lane = t & 63;
    const int wid  = t >> 6;
    const int wr   = wid >> 1;
    const int wc   = wid & 1;

    const int rowA = ti * 128;
    const int rowB = tj * 128;

    if (t < 128) labA[t] = labels[rowA + t];
    else         labB[t - 128] = labels[rowB + (t - 128)];

    frag_cd acc[4][4];
    #pragma unroll
    for (int m = 0; m < 4; ++m)
        #pragma unroll
        for (int n = 0; n < 4; ++n)
            acc[m][n] = (frag_cd){0.f, 0.f, 0.f, 0.f};

    const int g  = lane >> 4;
    const int rl = lane & 15;

    for (int kh = 0; kh < 2; ++kh) {
        __syncthreads();
        #pragma unroll
        for (int it = 0; it < 4; ++it) {
            const int c  = it * 256 + t;
            const int r  = c >> 3;
            const int c8 = c & 7;
            const float* srcA = X + (size_t)(rowA + r) * 128 + kh * 64 + c8 * 8;
            const float* srcB = X + (size_t)(rowB + r) * 128 + kh * 64 + c8 * 8;
            float4 a0 = *(const float4*)(srcA);
            float4 a1 = *(const float4*)(srcA + 4);
            float4 b0 = *(const float4*)(srcB);
            float4 b1 = *(const float4*)(srcB + 4);
            const int byte = r * 128 + (((c8 << 4)) ^ ((r & 7) << 4));
            frag_ab pa, pb;
            pa[0] = (short)f2bf(a0.x); pa[1] = (short)f2bf(a0.y);
            pa[2] = (short)f2bf(a0.z); pa[3] = (short)f2bf(a0.w);
            pa[4] = (short)f2bf(a1.x); pa[5] = (short)f2bf(a1.y);
            pa[6] = (short)f2bf(a1.z); pa[7] = (short)f2bf(a1.w);
            pb[0] = (short)f2bf(b0.x); pb[1] = (short)f2bf(b0.y);
            pb[2] = (short)f2bf(b0.z); pb[3] = (short)f2bf(b0.w);
            pb[4] = (short)f2bf(b1.x); pb[5] = (short)f2bf(b1.y);
            pb[6] = (short)f2bf(b1.z); pb[7] = (short)f2bf(b1.w);
            *(frag_ab*)((char*)ldsA + byte) = pa;
            *(frag_ab*)((char*)ldsB + byte) = pb;
        }
        __syncthreads();
        #pragma unroll
        for (int ks = 0; ks < 2; ++ks) {
            const int kbyte = ks * 64 + g * 16;
            frag_ab av[4], bv[4];
            #pragma unroll
            for (int m = 0; m < 4; ++m) {
                const int row = wr * 64 + m * 16 + rl;
                av[m] = *(const frag_ab*)((const char*)ldsA +
                            row * 128 + (kbyte ^ ((row & 7) << 4)));
            }
            #pragma unroll
            for (int n = 0; n < 4; ++n) {
                const int row = wc * 64 + n * 16 + rl;
                bv[n] = *(const frag_ab*)((const char*)ldsB +
                            row * 128 + (kbyte ^ ((row & 7) << 4)));
            }
            #pragma unroll
            for (int m = 0; m < 4; ++m)
                #pragma unroll
                for (int n = 0; n < 4; ++n)
                    acc[m][n] = __builtin_amdgcn_mfma_f32_16x16x32_bf16(
                        av[m], bv[n], acc[m][n], 0, 0, 0);
        }
    }

    float lsum = 0.f;
    const int oc  = lane & 15;
    const int orr = (lane >> 4) * 4;

    int lj[4];
    #pragma unroll
    for (int n = 0; n < 4; ++n) lj[n] = labB[wc * 64 + n * 16 + oc];

    #pragma unroll
    for (int m = 0; m < 4; ++m) {
        #pragma unroll
        for (int j = 0; j < 4; ++j) {
            const int li = labA[wr * 64 + m * 16 + orr + j];
            #pragma unroll
            for (int n = 0; n < 4; ++n) {
                const float d = acc[m][n][j];
                const float s = (li == lj[n]) ? 1.f : -1.f;
                lsum += fmaxf(fmaf(s, d - BETHE_C, ALPHA_C), 0.f);
            }
        }
    }

    const float w = (ti == tj) ? 1.f : 2.f;
    lsum *= w * inv_n;

    #pragma unroll
    for (int off = 32; off > 0; off >>= 1)
        lsum += __shfl_down(lsum, off, 64);

    if (lane == 0) wsum[wid] = lsum;
    __syncthreads();
    if (t == 0) atomicAdd(out, wsum[0] + wsum[1] + wsum[2] + wsum[3]);
}

extern "C" void kernel_launch(void* const* d_in, const int* in_sizes, int n_in,
                              void* d_out, int out_size, void* d_ws, size_t ws_size,
                              hipStream_t stream) {
    const float* X      = (const float*)d_in[0];
    const int*   labels = (const int*)d_in[1];
    float*       out    = (float*)d_out;

    const int N  = in_sizes[1];              // 8192
    const int NT = N / 128;                  // 64
    const int nblocks = NT * (NT + 1) / 2;   // 2080

    const size_t xb_bytes = (size_t)N * 128 * sizeof(unsigned short);  // 2 MB
    const size_t need     = xb_bytes + (size_t)nblocks * sizeof(float);

    if ((N % 128) == 0 && ws_size >= need) {
        unsigned short* Xb       = (unsigned short*)d_ws;
        float*          partials = (float*)((char*)d_ws + xb_bytes);
        const int cblocks = (N * 16 + 255) / 256;
        convert_kernel<<<cblocks, 256, 0, stream>>>(X, Xb, N);
        margin_tile_bf16<<<nblocks, 256, 0, stream>>>(Xb, labels, partials, NT, 1.0f / (float)N);
        reduce_kernel<<<1, 256, 0, stream>>>(partials, out, nblocks);
    } else {
        zero_kernel<<<1, 1, 0, stream>>>(out);
        margin_tile_kernel<<<nblocks, 256, 0, stream>>>(X, labels, out, NT, 1.0f / (float)N);
    }
}